// Round 3
// baseline (1642.931 us; speedup 1.0000x reference)
//
#include <hip/hip_runtime.h>
#include <hip/hip_bf16.h>
#include <math.h>

// Problem constants (verified against in_sizes at runtime where cheap)
constexpr int S_   = 4;
constexpr int MO   = 256;
constexpr int NO   = 128;
constexpr int FIN  = 384;   // MO + NO
#define CUTOFF_F 5.2f

__device__ __forceinline__ float gelu_tanh(float x) {
    // jax.nn.gelu default: approximate=True (tanh form)
    float u = 0.7978845608028654f * (x + 0.044715f * x * x * x);
    return 0.5f * x * (1.0f + tanhf(u));
}

// ---------------- decay ----------------
__global__ void decay_kernel(const float* __restrict__ dist, const float* __restrict__ fa_,
                             const float* __restrict__ pf_, float* __restrict__ decay, int P) {
    int i = blockIdx.x * blockDim.x + threadIdx.x;
    if (i >= P) return;
    float fa = fa_[0], pf = pf_[0];
    float d = dist[i];
    float x = fminf(fmaxf(d / CUTOFF_F, 0.0f), 1.0f - 1e-6f);
    float f = expf(1.0f - 1.0f / (1.0f - x * x));
    float w = (d < CUTOFF_F) ? f : 0.0f;
    decay[i] = pf * pf * expf(-(fa * fa) * d) * w;
}

// ---------------- species counting sort ----------------
// cnt layout: [0..3] counts, [4..7] seg offsets, [8..11] cursors
__global__ void init_counts(int* cnt) {
    if (threadIdx.x < 12) cnt[threadIdx.x] = 0;
}
__global__ void hist_kernel(const int* __restrict__ sp, int* cnt, int N) {
    int i = blockIdx.x * blockDim.x + threadIdx.x;
    if (i < N) {
        int s = sp[i];
        if (s >= 0 && s < S_) atomicAdd(&cnt[s], 1);
    }
}
__global__ void scan_kernel(int* cnt) {
    int off = 0;
    for (int s = 0; s < S_; ++s) { cnt[4 + s] = off; cnt[8 + s] = off; off += cnt[s]; }
}
__global__ void build_perm(const int* __restrict__ sp, int* cnt, int* __restrict__ perm, int N) {
    int i = blockIdx.x * blockDim.x + threadIdx.x;
    if (i < N) {
        int s = sp[i];
        if (s >= 0 && s < S_) {
            int pos = atomicAdd(&cnt[8 + s], 1);
            perm[pos] = i;
        }
    }
}

// ---------------- species-routed tiled fp32 GEMM ----------------
// C[row, :] = act(A[row, 0:K] @ W[s] + b[s]) for rows of species s (via perm).
// 64x64 tile, 256 threads, 4x4 microtile, TK=16.
template<int K, int NC, bool ACT>
__global__ void routed_gemm(const float* __restrict__ Aorig, int lda,
                            const float* __restrict__ W, const float* __restrict__ bias,
                            float* __restrict__ C, int ldc,
                            const int* __restrict__ cnt, const int* __restrict__ perm) {
    const int s = blockIdx.z;
    const int count = cnt[s];
    const int row0 = blockIdx.y * 64;
    if (row0 >= count) return;
    const int off = cnt[4 + s];
    const int c0 = blockIdx.x * 64;

    __shared__ float As[16][65];
    __shared__ float Bs[16][64];
    __shared__ int rowIdx[64];

    const int t = threadIdx.x;
    if (t < 64) {
        int ri = row0 + t;
        rowIdx[t] = (ri < count) ? perm[off + ri] : -1;
    }
    __syncthreads();

    const int ty = t >> 4, tx = t & 15;
    float acc[4][4] = {};
    const float* Wp = W + (size_t)s * K * NC;

    for (int k0 = 0; k0 < K; k0 += 16) {
#pragma unroll
        for (int p = 0; p < 4; ++p) {
            int e = p * 256 + t;
            int r = e >> 4, kk = e & 15;
            int g = rowIdx[r];
            As[kk][r] = (g >= 0) ? Aorig[(size_t)g * lda + k0 + kk] : 0.0f;
        }
#pragma unroll
        for (int p = 0; p < 4; ++p) {
            int e = p * 256 + t;
            int kk = e >> 6, cc = e & 63;
            Bs[kk][cc] = Wp[(size_t)(k0 + kk) * NC + c0 + cc];
        }
        __syncthreads();
#pragma unroll
        for (int kk = 0; kk < 16; ++kk) {
            float a[4], b[4];
#pragma unroll
            for (int i = 0; i < 4; ++i) a[i] = As[kk][ty * 4 + i];
#pragma unroll
            for (int j = 0; j < 4; ++j) b[j] = Bs[kk][tx * 4 + j];
#pragma unroll
            for (int i = 0; i < 4; ++i)
#pragma unroll
                for (int j = 0; j < 4; ++j)
                    acc[i][j] += a[i] * b[j];
        }
        __syncthreads();
    }

#pragma unroll
    for (int i = 0; i < 4; ++i) {
        int r = ty * 4 + i;
        int g = rowIdx[r];
        if (g < 0) continue;
#pragma unroll
        for (int j = 0; j < 4; ++j) {
            int col = c0 + tx * 4 + j;
            float v = acc[i][j] + bias[s * NC + col];
            if (ACT) v = gelu_tanh(v);
            C[(size_t)g * ldc + col] = v;
        }
    }
}

// ---------------- message passing ----------------
__global__ void zero_merged(float* __restrict__ feat, int N) {
    int i = blockIdx.x * blockDim.x + threadIdx.x;
    if (i < N * NO) {
        int n = i >> 7, j = i & 127;
        feat[(size_t)n * FIN + MO + j] = 0.0f;
    }
}

// For e in [0,2P): dst = ai[e]; src = ai[e<P ? P+e : e-P]; feat[dst, MO+j] += neigh[src, j]*decay[e%P]
__global__ void scatter_kernel(const float* __restrict__ neigh, const float* __restrict__ decay,
                               const int* __restrict__ ai, float* __restrict__ feat, int P) {
    int e = blockIdx.x * 2 + (threadIdx.x >> 7);
    int j = threadIdx.x & 127;
    if (e >= 2 * P) return;
    int p = (e < P) ? e : e - P;
    int dst = ai[e];
    int src = (e < P) ? ai[P + p] : ai[p];
    float v = neigh[(size_t)src * NO + j] * decay[p];
    atomicAdd(&feat[(size_t)dst * FIN + MO + j], v);
}

// ---------------- final head: pre = feat @ Wf[s] + bf[s]; also emit species ----------------
__global__ void final_kernel(const float* __restrict__ feat, const float* __restrict__ Wf,
                             const float* __restrict__ bf, const int* __restrict__ species,
                             float* __restrict__ out, int N) {
    int w = (int)((blockIdx.x * (size_t)blockDim.x + threadIdx.x) >> 6);
    int lane = threadIdx.x & 63;
    if (w >= N) return;
    int s = species[w];
    float acc = 0.0f;
    if (s >= 0) {
        const float* wp = Wf + (size_t)s * FIN;
        const float* fp = feat + (size_t)w * FIN;
        for (int k = lane; k < FIN; k += 64) acc += fp[k] * wp[k];
    }
    for (int o = 32; o > 0; o >>= 1) acc += __shfl_down(acc, o, 64);
    if (lane == 0) {
        float pre = (s >= 0) ? (acc + bf[s]) : 0.0f;
        out[2 * (size_t)N + w] = pre;      // pre
        out[w] = (float)s;                 // species as float
    }
}

// ---------------- per-batch charge correction ----------------
__global__ void charges_kernel(const float* __restrict__ pre_buf, const int* __restrict__ species,
                               const float* __restrict__ tc, float* __restrict__ out, int N, int A) {
    int b = blockIdx.x;
    int a = threadIdx.x;            // A == 128 expected (2 waves)
    int idx = b * A + a;
    float pre = pre_buf[idx];
    int sp = species[idx];
    bool mask = (sp != -1);

    float v = pre;
    int c = mask ? 1 : 0;
    for (int o = 32; o > 0; o >>= 1) {
        v += __shfl_down(v, o, 64);
        c += __shfl_down(c, o, 64);
    }
    __shared__ float ssum[2];
    __shared__ int scnt[2];
    int wid = threadIdx.x >> 6;
    if ((threadIdx.x & 63) == 0) { ssum[wid] = v; scnt[wid] = c; }
    __syncthreads();
    float total = ssum[0] + ssum[1];
    int nreal = scnt[0] + scnt[1];
    float ch = pre + (tc[b] - total) / (float)max(nreal, 1);
    out[(size_t)N + idx] = mask ? ch : 0.0f;
}

extern "C" void kernel_launch(void* const* d_in, const int* in_sizes, int n_in,
                              void* d_out, int out_size, void* d_ws, size_t ws_size,
                              hipStream_t stream) {
    const int*   species = (const int*)d_in[0];
    const float* aev     = (const float*)d_in[1];
    const int*   ai      = (const int*)d_in[2];
    const float* dist    = (const float*)d_in[3];
    const float* tc      = (const float*)d_in[4];
    const float* Wm0 = (const float*)d_in[5];  const float* bm0 = (const float*)d_in[6];
    const float* Wn0 = (const float*)d_in[7];  const float* bn0 = (const float*)d_in[8];
    const float* Wm1 = (const float*)d_in[9];  const float* bm1 = (const float*)d_in[10];
    const float* Wn1 = (const float*)d_in[11]; const float* bn1 = (const float*)d_in[12];
    const float* Wf  = (const float*)d_in[13]; const float* bf  = (const float*)d_in[14];
    const float* factor    = (const float*)d_in[15];
    const float* prefactor = (const float*)d_in[16];

    const int N   = in_sizes[0];
    const int AEV = in_sizes[1] / N;       // 1008
    const int P   = in_sizes[3];           // 262144
    const int B   = in_sizes[4];           // 256
    const int A   = N / B;                 // 128

    float* out = (float*)d_out;

    // workspace layout
    float* feat1 = (float*)d_ws;                         // N*FIN
    float* feat2 = feat1 + (size_t)N * FIN;              // N*FIN
    float* neigh = feat2 + (size_t)N * FIN;              // N*NO
    float* decay = neigh + (size_t)N * NO;               // P
    int*   perm  = (int*)(decay + P);                    // N
    int*   cnt   = perm + N;                             // 12

    // species sort + decay
    init_counts<<<1, 64, 0, stream>>>(cnt);
    hist_kernel<<<(N + 255) / 256, 256, 0, stream>>>(species, cnt, N);
    scan_kernel<<<1, 1, 0, stream>>>(cnt);
    build_perm<<<(N + 255) / 256, 256, 0, stream>>>(species, cnt, perm, N);
    decay_kernel<<<(P + 255) / 256, 256, 0, stream>>>(dist, factor, prefactor, decay, P);

    const int rt = (N + 63) / 64;
    dim3 blk(256);

    // pass 0
    routed_gemm<1008, 256, true><<<dim3(256 / 64, rt, S_), blk, 0, stream>>>(
        aev, AEV, Wm0, bm0, feat1, FIN, cnt, perm);
    routed_gemm<256, 128, true><<<dim3(128 / 64, rt, S_), blk, 0, stream>>>(
        feat1, FIN, Wn0, bn0, neigh, NO, cnt, perm);
    zero_merged<<<(N * NO + 255) / 256, 256, 0, stream>>>(feat1, N);
    scatter_kernel<<<P, 256, 0, stream>>>(neigh, decay, ai, feat1, P);

    // pass 1
    routed_gemm<384, 256, true><<<dim3(256 / 64, rt, S_), blk, 0, stream>>>(
        feat1, FIN, Wm1, bm1, feat2, FIN, cnt, perm);
    routed_gemm<256, 128, true><<<dim3(128 / 64, rt, S_), blk, 0, stream>>>(
        feat2, FIN, Wn1, bn1, neigh, NO, cnt, perm);
    zero_merged<<<(N * NO + 255) / 256, 256, 0, stream>>>(feat2, N);
    scatter_kernel<<<P, 256, 0, stream>>>(neigh, decay, ai, feat2, P);

    // head + charges
    final_kernel<<<(N * 64 + 255) / 256, 256, 0, stream>>>(feat2, Wf, bf, species, out, N);
    charges_kernel<<<B, A, 0, stream>>>(out + 2 * (size_t)N, species, tc, out, N, A);
}

// Round 4
// 1255.716 us; speedup vs baseline: 1.3084x; 1.3084x over previous
//
#include <hip/hip_runtime.h>
#include <hip/hip_bf16.h>
#include <math.h>

constexpr int S_  = 4;
constexpr int MO  = 256;
constexpr int NO  = 128;
constexpr int FIN = 384;
#define CUTOFF_F 5.2f

typedef short bf16x8 __attribute__((ext_vector_type(8)));   // 8 bf16 = 4 VGPRs
typedef float f32x16 __attribute__((ext_vector_type(16)));  // 32x32 MFMA acc

__device__ __forceinline__ float gelu_tanh(float x) {
    float u = 0.7978845608028654f * (x + 0.044715f * x * x * x);
    return 0.5f * x * (1.0f + tanhf(u));
}
__device__ __forceinline__ unsigned short f2bf(float x) {   // RNE
    unsigned u = __float_as_uint(x);
    u = (u + 0x7fffu + ((u >> 16) & 1u)) >> 16;
    return (unsigned short)u;
}
__device__ __forceinline__ float bf2f(unsigned short h) {
    return __uint_as_float(((unsigned)h) << 16);
}

// ---------------- decay ----------------
__global__ void decay_kernel(const float* __restrict__ dist, const float* __restrict__ fa_,
                             const float* __restrict__ pf_, float* __restrict__ decay, int P) {
    int i = blockIdx.x * blockDim.x + threadIdx.x;
    if (i >= P) return;
    float fa = fa_[0], pf = pf_[0];
    float d = dist[i];
    float x = fminf(fmaxf(d / CUTOFF_F, 0.0f), 1.0f - 1e-6f);
    float f = expf(1.0f - 1.0f / (1.0f - x * x));
    float w = (d < CUTOFF_F) ? f : 0.0f;
    decay[i] = pf * pf * expf(-(fa * fa) * d) * w;
}

// ---------------- species counting sort ----------------
__global__ void init_counts(int* cnt) { if (threadIdx.x < 12) cnt[threadIdx.x] = 0; }
__global__ void hist_kernel(const int* __restrict__ sp, int* cnt, int N) {
    int i = blockIdx.x * blockDim.x + threadIdx.x;
    if (i < N) { int s = sp[i]; if (s >= 0 && s < S_) atomicAdd(&cnt[s], 1); }
}
__global__ void scan_kernel(int* cnt) {
    int off = 0;
    for (int s = 0; s < S_; ++s) { cnt[4 + s] = off; cnt[8 + s] = off; off += cnt[s]; }
}
__global__ void build_perm(const int* __restrict__ sp, int* cnt, int* __restrict__ perm, int N) {
    int i = blockIdx.x * blockDim.x + threadIdx.x;
    if (i < N) {
        int s = sp[i];
        if (s >= 0 && s < S_) { int pos = atomicAdd(&cnt[8 + s], 1); perm[pos] = i; }
    }
}

// ---------------- casts ----------------
__global__ void cast_aev(const float* __restrict__ in, unsigned short* __restrict__ outb, int total4) {
    int i = blockIdx.x * blockDim.x + threadIdx.x;
    if (i >= total4) return;
    float4 v = ((const float4*)in)[i];
    ushort4 o; o.x = f2bf(v.x); o.y = f2bf(v.y); o.z = f2bf(v.z); o.w = f2bf(v.w);
    ((ushort4*)outb)[i] = o;
}

// merged_f [N][128] fp32 -> feat_bf[:, MO:MO+NO] bf16
__global__ void cast_merged(const float* __restrict__ mf, unsigned short* __restrict__ feat, int N) {
    int i = blockIdx.x * blockDim.x + threadIdx.x;
    if (i >= N * 32) return;
    int row = i >> 5, c4 = (i & 31) * 4;
    float4 v = *(const float4*)(mf + (size_t)row * NO + c4);
    ushort4 o; o.x = f2bf(v.x); o.y = f2bf(v.y); o.z = f2bf(v.z); o.w = f2bf(v.w);
    *(ushort4*)(feat + (size_t)row * FIN + MO + c4) = o;
}

// W [S][K][NC] fp32 -> Wt [S][NC][K] bf16
__global__ void transpose_cast(const float* __restrict__ W, unsigned short* __restrict__ Wt,
                               int K, int NC) {
    __shared__ float tile[32][33];
    int s = blockIdx.z;
    int nb = blockIdx.x * 32, kb = blockIdx.y * 32;
    int tx = threadIdx.x & 31, ty = threadIdx.x >> 5;  // 256 thr: ty 0..7
    const float* Wb = W + (size_t)s * K * NC;
    unsigned short* Wo = Wt + (size_t)s * NC * K;
#pragma unroll
    for (int i = 0; i < 4; ++i) {
        int k = kb + ty + i * 8;
        tile[ty + i * 8][tx] = (k < K) ? Wb[(size_t)k * NC + nb + tx] : 0.0f;
    }
    __syncthreads();
#pragma unroll
    for (int i = 0; i < 4; ++i) {
        int n = nb + ty + i * 8;
        int k = kb + tx;
        if (k < K) Wo[(size_t)n * K + k] = f2bf(tile[tx][ty + i * 8]);
    }
}

// ---------------- species-routed bf16 MFMA GEMM ----------------
// C[g,:] = act(A[g,0:K] @ W[s] + b[s]) for gathered rows; Wt transposed [S][NC][K].
// Block: 128x128 tile, 4 waves (2x2), per-wave 64x64 via 2x2 frags of 32x32x16.
template<int K, int NC, bool ACT>
__launch_bounds__(256, 2)
__global__ void mfma_gemm(const unsigned short* __restrict__ A, int lda,
                          const unsigned short* __restrict__ Wt,
                          const float* __restrict__ bias,
                          unsigned short* __restrict__ C, int ldc,
                          const int* __restrict__ cnt, const int* __restrict__ perm) {
    const int s = blockIdx.z;
    const int count = cnt[s];
    const int row0 = blockIdx.y * 128;
    if (row0 >= count) return;
    const int off = cnt[4 + s];
    const int c0 = blockIdx.x * 128;

    __shared__ unsigned short As[128 * 40];  // row stride 40 bf16 = 80 B (16B-aligned)
    __shared__ unsigned short Bs[128 * 40];
    __shared__ int rix[128];

    const int t = threadIdx.x;
    const int lane = t & 63, wave = t >> 6;
    const int wm = wave >> 1, wn = wave & 1;
    const int l31 = lane & 31, lhi = lane >> 5;

    if (t < 128) {
        int ri = row0 + t;
        rix[t] = (ri < count) ? perm[off + ri] : -1;
    }
    __syncthreads();

    const int r2 = t >> 1, half = t & 1;     // staging: 2 threads per LDS row
    const int gA = rix[r2];
    const unsigned short* wrow = Wt + ((size_t)s * NC + c0 + r2) * K;

    f32x16 acc00 = {}, acc01 = {}, acc10 = {}, acc11 = {};
    const float4 zf4 = make_float4(0.f, 0.f, 0.f, 0.f);

    for (int k0 = 0; k0 < K; k0 += 32) {
        const int kk = k0 + half * 16;
        const bool v = (kk < K);           // K%16==0 so chunk fully valid or fully out
        float4 a0 = zf4, a1 = zf4, b0 = zf4, b1 = zf4;
        if (v) {
            if (gA >= 0) {
                const float4* p = (const float4*)(A + (size_t)gA * lda + kk);
                a0 = p[0]; a1 = p[1];
            }
            const float4* q = (const float4*)(wrow + kk);
            b0 = q[0]; b1 = q[1];
        }
        __syncthreads();   // previous iter's frag reads done
        *(float4*)(&As[r2 * 40 + half * 16])     = a0;
        *(float4*)(&As[r2 * 40 + half * 16 + 8]) = a1;
        *(float4*)(&Bs[r2 * 40 + half * 16])     = b0;
        *(float4*)(&Bs[r2 * 40 + half * 16 + 8]) = b1;
        __syncthreads();
#pragma unroll
        for (int ks = 0; ks < 2; ++ks) {
            const int ch = (ks * 2 + lhi) * 8;  // k-chunk offset in bf16 units
            bf16x8 fa0 = *(const bf16x8*)(&As[(wm * 64 +  0 + l31) * 40 + ch]);
            bf16x8 fa1 = *(const bf16x8*)(&As[(wm * 64 + 32 + l31) * 40 + ch]);
            bf16x8 fb0 = *(const bf16x8*)(&Bs[(wn * 64 +  0 + l31) * 40 + ch]);
            bf16x8 fb1 = *(const bf16x8*)(&Bs[(wn * 64 + 32 + l31) * 40 + ch]);
            acc00 = __builtin_amdgcn_mfma_f32_32x32x16_bf16(fa0, fb0, acc00, 0, 0, 0);
            acc01 = __builtin_amdgcn_mfma_f32_32x32x16_bf16(fa0, fb1, acc01, 0, 0, 0);
            acc10 = __builtin_amdgcn_mfma_f32_32x32x16_bf16(fa1, fb0, acc10, 0, 0, 0);
            acc11 = __builtin_amdgcn_mfma_f32_32x32x16_bf16(fa1, fb1, acc11, 0, 0, 0);
        }
    }

    const float* bp = bias + s * NC;
    auto store = [&](const f32x16& vv, int fm, int fn) {
        int col = c0 + wn * 64 + fn * 32 + l31;
        float bia = bp[col];
#pragma unroll
        for (int reg = 0; reg < 16; ++reg) {
            int frow = (reg & 3) + 8 * (reg >> 2) + 4 * lhi;   // verified C/D layout
            int r = wm * 64 + fm * 32 + frow;
            int g = rix[r];
            if (g >= 0) {
                float x = vv[reg] + bia;
                if (ACT) x = gelu_tanh(x);
                C[(size_t)g * ldc + col] = f2bf(x);
            }
        }
    };
    store(acc00, 0, 0); store(acc01, 0, 1); store(acc10, 1, 0); store(acc11, 1, 1);
}

// ---------------- message passing scatter (bf16 neigh -> fp32 atomics) ----------------
__global__ void scatter_kernel(const unsigned short* __restrict__ neigh, const float* __restrict__ decay,
                               const int* __restrict__ ai, float* __restrict__ merged, int P) {
    int e = blockIdx.x * 2 + (threadIdx.x >> 7);
    int j = threadIdx.x & 127;
    int p = (e < P) ? e : e - P;
    int dst = ai[e];
    int src = (e < P) ? ai[P + p] : ai[p];
    float v = bf2f(neigh[(size_t)src * NO + j]) * decay[p];
    atomicAdd(&merged[(size_t)dst * NO + j], v);
}

// ---------------- final head ----------------
__global__ void final_kernel(const unsigned short* __restrict__ int1, const float* __restrict__ merged,
                             const float* __restrict__ Wf, const float* __restrict__ bfb,
                             const int* __restrict__ species, float* __restrict__ out, int N) {
    int w = (int)((blockIdx.x * (size_t)blockDim.x + threadIdx.x) >> 6);
    int lane = threadIdx.x & 63;
    if (w >= N) return;
    int s = species[w];
    float acc = 0.0f;
    if (s >= 0) {
        const float* wp = Wf + (size_t)s * FIN;
        for (int k = lane; k < MO; k += 64) acc += bf2f(int1[(size_t)w * MO + k]) * wp[k];
        for (int k = lane; k < NO; k += 64) acc += merged[(size_t)w * NO + k] * wp[MO + k];
    }
    for (int o = 32; o > 0; o >>= 1) acc += __shfl_down(acc, o, 64);
    if (lane == 0) {
        float pre = (s >= 0) ? (acc + bfb[s]) : 0.0f;
        out[2 * (size_t)N + w] = pre;
        out[w] = (float)s;
    }
}

// ---------------- per-batch charge correction ----------------
__global__ void charges_kernel(const float* __restrict__ pre_buf, const int* __restrict__ species,
                               const float* __restrict__ tc, float* __restrict__ out, int N, int A) {
    int b = blockIdx.x;
    int a = threadIdx.x;
    int idx = b * A + a;
    float pre = pre_buf[idx];
    int sp = species[idx];
    bool mask = (sp != -1);
    float v = pre;
    int c = mask ? 1 : 0;
    for (int o = 32; o > 0; o >>= 1) {
        v += __shfl_down(v, o, 64);
        c += __shfl_down(c, o, 64);
    }
    __shared__ float ssum[2];
    __shared__ int scnt[2];
    int wid = threadIdx.x >> 6;
    if ((threadIdx.x & 63) == 0) { ssum[wid] = v; scnt[wid] = c; }
    __syncthreads();
    float total = ssum[0] + ssum[1];
    int nreal = scnt[0] + scnt[1];
    float ch = pre + (tc[b] - total) / (float)max(nreal, 1);
    out[(size_t)N + idx] = mask ? ch : 0.0f;
}

extern "C" void kernel_launch(void* const* d_in, const int* in_sizes, int n_in,
                              void* d_out, int out_size, void* d_ws, size_t ws_size,
                              hipStream_t stream) {
    const int*   species = (const int*)d_in[0];
    const float* aev     = (const float*)d_in[1];
    const int*   ai      = (const int*)d_in[2];
    const float* dist    = (const float*)d_in[3];
    const float* tc      = (const float*)d_in[4];
    const float* Wm0 = (const float*)d_in[5];  const float* bm0 = (const float*)d_in[6];
    const float* Wn0 = (const float*)d_in[7];  const float* bn0 = (const float*)d_in[8];
    const float* Wm1 = (const float*)d_in[9];  const float* bm1 = (const float*)d_in[10];
    const float* Wn1 = (const float*)d_in[11]; const float* bn1 = (const float*)d_in[12];
    const float* Wf  = (const float*)d_in[13]; const float* bf  = (const float*)d_in[14];
    const float* factor    = (const float*)d_in[15];
    const float* prefactor = (const float*)d_in[16];

    const int N   = in_sizes[0];
    const int AEV = in_sizes[1] / N;       // 1008
    const int P   = in_sizes[3];
    const int B   = in_sizes[4];
    const int A   = N / B;

    float* out = (float*)d_out;

    // ---- workspace layout (aligned 256 B) ----
    char* base = (char*)d_ws;
    size_t o = 0;
    auto take = [&](size_t bytes) -> char* {
        o = (o + 255) & ~(size_t)255;
        char* p = base + o; o += bytes; return p;
    };
    unsigned short* feat1_bf = (unsigned short*)take((size_t)N * FIN * 2);
    unsigned short* int1_bf  = (unsigned short*)take((size_t)N * MO * 2);
    char* region             = take((size_t)N * AEV * 2);   // aev_bf, later neigh_bf+merged_f
    unsigned short* aev_bf   = (unsigned short*)region;
    unsigned short* neigh_bf = (unsigned short*)region;                       // after GEMM1
    float* merged_f          = (float*)(region + (((size_t)N * NO * 2 + 255) & ~(size_t)255));
    float* decay             = (float*)take((size_t)P * 4);
    unsigned short* Wm0t = (unsigned short*)take((size_t)S_ * MO * AEV * 2);
    unsigned short* Wn0t = (unsigned short*)take((size_t)S_ * NO * MO * 2);
    unsigned short* Wm1t = (unsigned short*)take((size_t)S_ * MO * FIN * 2);
    unsigned short* Wn1t = (unsigned short*)take((size_t)S_ * NO * MO * 2);
    int* perm = (int*)take((size_t)N * 4);
    int* cnt  = (int*)take(64);

    // ---- species sort + decay + casts/transposes ----
    init_counts<<<1, 64, 0, stream>>>(cnt);
    hist_kernel<<<(N + 255) / 256, 256, 0, stream>>>(species, cnt, N);
    scan_kernel<<<1, 1, 0, stream>>>(cnt);
    build_perm<<<(N + 255) / 256, 256, 0, stream>>>(species, cnt, perm, N);
    decay_kernel<<<(P + 255) / 256, 256, 0, stream>>>(dist, factor, prefactor, decay, P);

    const int tot4 = N * (AEV / 4);
    cast_aev<<<(tot4 + 255) / 256, 256, 0, stream>>>(aev, aev_bf, tot4);
    transpose_cast<<<dim3(MO / 32, (AEV + 31) / 32, S_), 256, 0, stream>>>(Wm0, Wm0t, AEV, MO);
    transpose_cast<<<dim3(NO / 32, MO / 32, S_), 256, 0, stream>>>(Wn0, Wn0t, MO, NO);
    transpose_cast<<<dim3(MO / 32, FIN / 32, S_), 256, 0, stream>>>(Wm1, Wm1t, FIN, MO);
    transpose_cast<<<dim3(NO / 32, MO / 32, S_), 256, 0, stream>>>(Wn1, Wn1t, MO, NO);

    const int rb = (N + 127) / 128;

    // ---- pass 0 ----
    mfma_gemm<1008, 256, true><<<dim3(2, rb, S_), 256, 0, stream>>>(
        aev_bf, AEV, Wm0t, bm0, feat1_bf, FIN, cnt, perm);
    mfma_gemm<256, 128, true><<<dim3(1, rb, S_), 256, 0, stream>>>(
        feat1_bf, FIN, Wn0t, bn0, neigh_bf, NO, cnt, perm);
    hipMemsetAsync(merged_f, 0, (size_t)N * NO * 4, stream);
    scatter_kernel<<<P, 256, 0, stream>>>(neigh_bf, decay, ai, merged_f, P);
    cast_merged<<<(N * 32 + 255) / 256, 256, 0, stream>>>(merged_f, feat1_bf, N);

    // ---- pass 1 ----
    mfma_gemm<384, 256, true><<<dim3(2, rb, S_), 256, 0, stream>>>(
        feat1_bf, FIN, Wm1t, bm1, int1_bf, MO, cnt, perm);
    mfma_gemm<256, 128, true><<<dim3(1, rb, S_), 256, 0, stream>>>(
        int1_bf, MO, Wn1t, bn1, neigh_bf, NO, cnt, perm);
    hipMemsetAsync(merged_f, 0, (size_t)N * NO * 4, stream);
    scatter_kernel<<<P, 256, 0, stream>>>(neigh_bf, decay, ai, merged_f, P);

    // ---- head + charges (head reads bf16 internal + fp32 merged directly) ----
    final_kernel<<<(N * 64 + 255) / 256, 256, 0, stream>>>(
        int1_bf, merged_f, Wf, bf, species, out, N);
    charges_kernel<<<B, A, 0, stream>>>(out + 2 * (size_t)N, species, tc, out, N, A);
}

// Round 6
// 1102.964 us; speedup vs baseline: 1.4896x; 1.1385x over previous
//
#include <hip/hip_runtime.h>
#include <hip/hip_bf16.h>
#include <math.h>

constexpr int S_  = 4;
constexpr int MO  = 256;
constexpr int NO  = 128;
constexpr int FIN = 384;
#define CUTOFF_F 5.2f

typedef short bf16x8 __attribute__((ext_vector_type(8)));   // 8 bf16 = 4 VGPRs
typedef float f32x16 __attribute__((ext_vector_type(16)));  // 32x32 MFMA acc

__device__ __forceinline__ float gelu_tanh(float x) {
    float u = 0.7978845608028654f * (x + 0.044715f * x * x * x);
    return 0.5f * x * (1.0f + tanhf(u));
}
__device__ __forceinline__ unsigned short f2bf(float x) {   // RNE
    unsigned u = __float_as_uint(x);
    u = (u + 0x7fffu + ((u >> 16) & 1u)) >> 16;
    return (unsigned short)u;
}
__device__ __forceinline__ float bf2f(unsigned short h) {
    return __uint_as_float(((unsigned)h) << 16);
}

// ---------------- decay ----------------
__global__ void decay_kernel(const float* __restrict__ dist, const float* __restrict__ fa_,
                             const float* __restrict__ pf_, float* __restrict__ decay, int P) {
    int i = blockIdx.x * blockDim.x + threadIdx.x;
    if (i >= P) return;
    float fa = fa_[0], pf = pf_[0];
    float d = dist[i];
    float x = fminf(fmaxf(d / CUTOFF_F, 0.0f), 1.0f - 1e-6f);
    float f = expf(1.0f - 1.0f / (1.0f - x * x));
    float w = (d < CUTOFF_F) ? f : 0.0f;
    decay[i] = pf * pf * expf(-(fa * fa) * d) * w;
}

// ---------------- species counting sort ----------------
__global__ void init_counts(int* cnt) { if (threadIdx.x < 12) cnt[threadIdx.x] = 0; }
__global__ void hist_kernel(const int* __restrict__ sp, int* cnt, int N) {
    int i = blockIdx.x * blockDim.x + threadIdx.x;
    if (i < N) { int s = sp[i]; if (s >= 0 && s < S_) atomicAdd(&cnt[s], 1); }
}
__global__ void scan_kernel(int* cnt) {
    int off = 0;
    for (int s = 0; s < S_; ++s) { cnt[4 + s] = off; cnt[8 + s] = off; off += cnt[s]; }
}
__global__ void build_perm(const int* __restrict__ sp, int* cnt, int* __restrict__ perm, int N) {
    int i = blockIdx.x * blockDim.x + threadIdx.x;
    if (i < N) {
        int s = sp[i];
        if (s >= 0 && s < S_) { int pos = atomicAdd(&cnt[8 + s], 1); perm[pos] = i; }
    }
}

// ---------------- edge CSR build (dst-sorted adjacency) ----------------
__global__ void edge_count(const int* __restrict__ ai, int* __restrict__ degree, int P2) {
    int e = blockIdx.x * blockDim.x + threadIdx.x;
    if (e < P2) atomicAdd(&degree[ai[e]], 1);
}
// single block, 1024 threads; N multiple of 1024
__global__ void scan_rowptr(const int* __restrict__ degree, int* __restrict__ rowptr,
                            int* __restrict__ cursor, int N) {
    __shared__ int lds[1024];
    int t = threadIdx.x;
    int per = N / 1024;
    int base = t * per;
    int sum = 0;
    for (int i = 0; i < per; ++i) sum += degree[base + i];
    lds[t] = sum;
    __syncthreads();
    int v = sum;
    for (int ofs = 1; ofs < 1024; ofs <<= 1) {
        int add = (t >= ofs) ? lds[t - ofs] : 0;
        __syncthreads();
        v += add;
        lds[t] = v;
        __syncthreads();
    }
    int run = v - sum;   // exclusive prefix
    for (int i = 0; i < per; ++i) {
        int d = degree[base + i];
        rowptr[base + i] = run;
        cursor[base + i] = run;
        run += d;
    }
    if (t == 1023) rowptr[N] = run;
}
__global__ void edge_fill(const int* __restrict__ ai, const float* __restrict__ decay,
                          int* __restrict__ cursor, int* __restrict__ col,
                          float* __restrict__ wgt, int P) {
    int e = blockIdx.x * blockDim.x + threadIdx.x;
    if (e >= 2 * P) return;
    int p = (e < P) ? e : e - P;
    int dst = ai[e];
    int src = (e < P) ? ai[P + p] : ai[p];
    int pos = atomicAdd(&cursor[dst], 1);
    col[pos] = src;
    wgt[pos] = decay[p];
}

// ---------------- casts ----------------
__global__ void cast_aev(const float* __restrict__ in, unsigned short* __restrict__ outb, int total4) {
    int i = blockIdx.x * blockDim.x + threadIdx.x;
    if (i >= total4) return;
    float4 v = ((const float4*)in)[i];
    ushort4 o; o.x = f2bf(v.x); o.y = f2bf(v.y); o.z = f2bf(v.z); o.w = f2bf(v.w);
    ((ushort4*)outb)[i] = o;
}

// W [S][K][NC] fp32 -> Wt [S][NC][K] bf16
__global__ void transpose_cast(const float* __restrict__ W, unsigned short* __restrict__ Wt,
                               int K, int NC) {
    __shared__ float tile[32][33];
    int s = blockIdx.z;
    int nb = blockIdx.x * 32, kb = blockIdx.y * 32;
    int tx = threadIdx.x & 31, ty = threadIdx.x >> 5;
    const float* Wb = W + (size_t)s * K * NC;
    unsigned short* Wo = Wt + (size_t)s * NC * K;
#pragma unroll
    for (int i = 0; i < 4; ++i) {
        int k = kb + ty + i * 8;
        tile[ty + i * 8][tx] = (k < K) ? Wb[(size_t)k * NC + nb + tx] : 0.0f;
    }
    __syncthreads();
#pragma unroll
    for (int i = 0; i < 4; ++i) {
        int n = nb + ty + i * 8;
        int k = kb + tx;
        if (k < K) Wo[(size_t)n * K + k] = f2bf(tile[tx][ty + i * 8]);
    }
}

// ---------------- species-routed bf16 MFMA GEMM ----------------
template<int K, int NC, bool ACT>
__launch_bounds__(256, 2)
__global__ void mfma_gemm(const unsigned short* __restrict__ A, int lda,
                          const unsigned short* __restrict__ Wt,
                          const float* __restrict__ bias,
                          unsigned short* __restrict__ C, int ldc,
                          const int* __restrict__ cnt, const int* __restrict__ perm) {
    const int s = blockIdx.z;
    const int count = cnt[s];
    const int row0 = blockIdx.y * 128;
    if (row0 >= count) return;
    const int off = cnt[4 + s];
    const int c0 = blockIdx.x * 128;

    __shared__ unsigned short As[128 * 40];
    __shared__ unsigned short Bs[128 * 40];
    __shared__ int rix[128];

    const int t = threadIdx.x;
    const int lane = t & 63, wave = t >> 6;
    const int wm = wave >> 1, wn = wave & 1;
    const int l31 = lane & 31, lhi = lane >> 5;

    if (t < 128) {
        int ri = row0 + t;
        rix[t] = (ri < count) ? perm[off + ri] : -1;
    }
    __syncthreads();

    const int r2 = t >> 1, half = t & 1;
    const int gA = rix[r2];
    const unsigned short* wrow = Wt + ((size_t)s * NC + c0 + r2) * K;

    f32x16 acc00 = {}, acc01 = {}, acc10 = {}, acc11 = {};
    const float4 zf4 = make_float4(0.f, 0.f, 0.f, 0.f);

    for (int k0 = 0; k0 < K; k0 += 32) {
        const int kk = k0 + half * 16;
        const bool v = (kk < K);
        float4 a0 = zf4, a1 = zf4, b0 = zf4, b1 = zf4;
        if (v) {
            if (gA >= 0) {
                const float4* p = (const float4*)(A + (size_t)gA * lda + kk);
                a0 = p[0]; a1 = p[1];
            }
            const float4* q = (const float4*)(wrow + kk);
            b0 = q[0]; b1 = q[1];
        }
        __syncthreads();
        *(float4*)(&As[r2 * 40 + half * 16])     = a0;
        *(float4*)(&As[r2 * 40 + half * 16 + 8]) = a1;
        *(float4*)(&Bs[r2 * 40 + half * 16])     = b0;
        *(float4*)(&Bs[r2 * 40 + half * 16 + 8]) = b1;
        __syncthreads();
#pragma unroll
        for (int ks = 0; ks < 2; ++ks) {
            const int ch = (ks * 2 + lhi) * 8;
            bf16x8 fa0 = *(const bf16x8*)(&As[(wm * 64 +  0 + l31) * 40 + ch]);
            bf16x8 fa1 = *(const bf16x8*)(&As[(wm * 64 + 32 + l31) * 40 + ch]);
            bf16x8 fb0 = *(const bf16x8*)(&Bs[(wn * 64 +  0 + l31) * 40 + ch]);
            bf16x8 fb1 = *(const bf16x8*)(&Bs[(wn * 64 + 32 + l31) * 40 + ch]);
            acc00 = __builtin_amdgcn_mfma_f32_32x32x16_bf16(fa0, fb0, acc00, 0, 0, 0);
            acc01 = __builtin_amdgcn_mfma_f32_32x32x16_bf16(fa0, fb1, acc01, 0, 0, 0);
            acc10 = __builtin_amdgcn_mfma_f32_32x32x16_bf16(fa1, fb0, acc10, 0, 0, 0);
            acc11 = __builtin_amdgcn_mfma_f32_32x32x16_bf16(fa1, fb1, acc11, 0, 0, 0);
        }
    }

    const float* bp = bias + s * NC;
    auto store = [&](const f32x16& vv, int fm, int fn) {
        int col = c0 + wn * 64 + fn * 32 + l31;
        float bia = bp[col];
#pragma unroll
        for (int reg = 0; reg < 16; ++reg) {
            int frow = (reg & 3) + 8 * (reg >> 2) + 4 * lhi;
            int r = wm * 64 + fm * 32 + frow;
            int g = rix[r];
            if (g >= 0) {
                float x = vv[reg] + bia;
                if (ACT) x = gelu_tanh(x);
                C[(size_t)g * ldc + col] = f2bf(x);
            }
        }
    };
    store(acc00, 0, 0); store(acc01, 0, 1); store(acc10, 1, 0); store(acc11, 1, 1);
}

// ---------------- CSR gather-reduce (replaces atomic scatter) ----------------
// One wave per dst row; lane owns 2 columns (ushort2 = 4 B).
// MODE 0: write bf16 into feat[:, MO:MO+NO];  MODE 1: write fp32 merged.
template<int MODE>
__global__ void gather_rows(const unsigned short* __restrict__ neigh,
                            const int* __restrict__ rowptr, const int* __restrict__ col,
                            const float* __restrict__ wgt,
                            unsigned short* __restrict__ featout,
                            float* __restrict__ mergedout) {
    int row = blockIdx.x * 4 + (threadIdx.x >> 6);
    int lane = threadIdx.x & 63;
    int b = rowptr[row], e = rowptr[row + 1];
    int j = lane * 2;
    float a0 = 0.f, a1 = 0.f;
    for (int i = b; i < e; ++i) {
        int src = col[i];
        float w = wgt[i];
        unsigned pk = *(const unsigned*)(neigh + (size_t)src * NO + j);
        a0 += bf2f((unsigned short)(pk & 0xffffu)) * w;
        a1 += bf2f((unsigned short)(pk >> 16)) * w;
    }
    if (MODE == 0) {
        unsigned short o0 = f2bf(a0), o1 = f2bf(a1);
        *(unsigned*)(featout + (size_t)row * FIN + MO + j) = ((unsigned)o1 << 16) | (unsigned)o0;
    } else {
        float2 o; o.x = a0; o.y = a1;
        *(float2*)(mergedout + (size_t)row * NO + j) = o;
    }
}

// ---------------- final head ----------------
__global__ void final_kernel(const unsigned short* __restrict__ int1, const float* __restrict__ merged,
                             const float* __restrict__ Wf, const float* __restrict__ bfb,
                             const int* __restrict__ species, float* __restrict__ out, int N) {
    int w = (int)((blockIdx.x * (size_t)blockDim.x + threadIdx.x) >> 6);
    int lane = threadIdx.x & 63;
    if (w >= N) return;
    int s = species[w];
    float acc = 0.0f;
    if (s >= 0) {
        const float* wp = Wf + (size_t)s * FIN;
        for (int k = lane; k < MO; k += 64) acc += bf2f(int1[(size_t)w * MO + k]) * wp[k];
        for (int k = lane; k < NO; k += 64) acc += merged[(size_t)w * NO + k] * wp[MO + k];
    }
    for (int o = 32; o > 0; o >>= 1) acc += __shfl_down(acc, o, 64);
    if (lane == 0) {
        float pre = (s >= 0) ? (acc + bfb[s]) : 0.0f;
        out[2 * (size_t)N + w] = pre;
        out[w] = (float)s;
    }
}

// ---------------- per-batch charge correction ----------------
__global__ void charges_kernel(const float* __restrict__ pre_buf, const int* __restrict__ species,
                               const float* __restrict__ tc, float* __restrict__ out, int N, int A) {
    int b = blockIdx.x;
    int a = threadIdx.x;
    int idx = b * A + a;
    float pre = pre_buf[idx];
    int sp = species[idx];
    bool mask = (sp != -1);
    float v = pre;
    int c = mask ? 1 : 0;
    for (int o = 32; o > 0; o >>= 1) {
        v += __shfl_down(v, o, 64);
        c += __shfl_down(c, o, 64);
    }
    __shared__ float ssum[2];
    __shared__ int scnt[2];
    int wid = threadIdx.x >> 6;
    if ((threadIdx.x & 63) == 0) { ssum[wid] = v; scnt[wid] = c; }
    __syncthreads();
    float total = ssum[0] + ssum[1];
    int nreal = scnt[0] + scnt[1];
    float ch = pre + (tc[b] - total) / (float)max(nreal, 1);
    out[(size_t)N + idx] = mask ? ch : 0.0f;
}

extern "C" void kernel_launch(void* const* d_in, const int* in_sizes, int n_in,
                              void* d_out, int out_size, void* d_ws, size_t ws_size,
                              hipStream_t stream) {
    const int*   species = (const int*)d_in[0];
    const float* aev     = (const float*)d_in[1];
    const int*   ai      = (const int*)d_in[2];
    const float* dist    = (const float*)d_in[3];
    const float* tc      = (const float*)d_in[4];
    const float* Wm0 = (const float*)d_in[5];  const float* bm0 = (const float*)d_in[6];
    const float* Wn0 = (const float*)d_in[7];  const float* bn0 = (const float*)d_in[8];
    const float* Wm1 = (const float*)d_in[9];  const float* bm1 = (const float*)d_in[10];
    const float* Wn1 = (const float*)d_in[11]; const float* bn1 = (const float*)d_in[12];
    const float* Wf  = (const float*)d_in[13]; const float* bf  = (const float*)d_in[14];
    const float* factor    = (const float*)d_in[15];
    const float* prefactor = (const float*)d_in[16];

    const int N   = in_sizes[0];
    const int AEV = in_sizes[1] / N;       // 1008
    const int P   = in_sizes[3];
    const int B   = in_sizes[4];
    const int A   = N / B;

    float* out = (float*)d_out;

    // ---- workspace layout ----
    char* base = (char*)d_ws;
    size_t o = 0;
    auto take = [&](size_t bytes) -> char* {
        o = (o + 255) & ~(size_t)255;
        char* p = base + o; o += bytes; return p;
    };
    unsigned short* feat1_bf = (unsigned short*)take((size_t)N * FIN * 2);
    unsigned short* int1_bf  = (unsigned short*)take((size_t)N * MO * 2);
    char* region             = take((size_t)N * AEV * 2);
    // region overlay:
    //   [0, 66MB)           aev_bf              (dead after gemm1)
    //   [0, 8MB)            neigh_bf            (gemm2/gemm4 output)
    //   [8MB, 24MB)         merged_f  (fp32, pass-1 only)
    //   [24MB, ~28.5MB)     CSR: rowptr, cursor, degree, col, wgt  (built after gemm1)
    unsigned short* aev_bf   = (unsigned short*)region;
    unsigned short* neigh_bf = (unsigned short*)region;
    size_t roff = ((size_t)N * NO * 2 + 255) & ~(size_t)255;
    float* merged_f = (float*)(region + roff);
    roff += (size_t)N * NO * 4;
    roff = (roff + 255) & ~(size_t)255;
    int* rowptr = (int*)(region + roff);  roff += (size_t)(N + 1) * 4; roff = (roff + 255) & ~(size_t)255;
    int* cursor = (int*)(region + roff);  roff += (size_t)N * 4;       roff = (roff + 255) & ~(size_t)255;
    int* degree = (int*)(region + roff);  roff += (size_t)N * 4;       roff = (roff + 255) & ~(size_t)255;
    int* ecol   = (int*)(region + roff);  roff += (size_t)2 * P * 4;   roff = (roff + 255) & ~(size_t)255;
    float* ewgt = (float*)(region + roff);
    float* decay = (float*)take((size_t)P * 4);
    unsigned short* Wm0t = (unsigned short*)take((size_t)S_ * MO * AEV * 2);
    unsigned short* Wn0t = (unsigned short*)take((size_t)S_ * NO * MO * 2);
    unsigned short* Wm1t = (unsigned short*)take((size_t)S_ * MO * FIN * 2);
    unsigned short* Wn1t = (unsigned short*)take((size_t)S_ * NO * MO * 2);
    int* perm = (int*)take((size_t)N * 4);
    int* cnt  = (int*)take(64);

    // ---- species sort + decay + casts/transposes ----
    init_counts<<<1, 64, 0, stream>>>(cnt);
    hist_kernel<<<(N + 255) / 256, 256, 0, stream>>>(species, cnt, N);
    scan_kernel<<<1, 1, 0, stream>>>(cnt);
    build_perm<<<(N + 255) / 256, 256, 0, stream>>>(species, cnt, perm, N);
    decay_kernel<<<(P + 255) / 256, 256, 0, stream>>>(dist, factor, prefactor, decay, P);

    const int tot4 = N * (AEV / 4);
    cast_aev<<<(tot4 + 255) / 256, 256, 0, stream>>>(aev, aev_bf, tot4);
    transpose_cast<<<dim3(MO / 32, (AEV + 31) / 32, S_), 256, 0, stream>>>(Wm0, Wm0t, AEV, MO);
    transpose_cast<<<dim3(NO / 32, MO / 32, S_), 256, 0, stream>>>(Wn0, Wn0t, MO, NO);
    transpose_cast<<<dim3(MO / 32, FIN / 32, S_), 256, 0, stream>>>(Wm1, Wm1t, FIN, MO);
    transpose_cast<<<dim3(NO / 32, MO / 32, S_), 256, 0, stream>>>(Wn1, Wn1t, MO, NO);

    const int rb = (N + 127) / 128;

    // ---- pass 0: big GEMM first (aev_bf dies here), then CSR build in its memory ----
    mfma_gemm<1008, 256, true><<<dim3(2, rb, S_), 256, 0, stream>>>(
        aev_bf, AEV, Wm0t, bm0, feat1_bf, FIN, cnt, perm);

    hipMemsetAsync(degree, 0, (size_t)N * 4, stream);
    edge_count<<<(2 * P + 255) / 256, 256, 0, stream>>>(ai, degree, 2 * P);
    scan_rowptr<<<1, 1024, 0, stream>>>(degree, rowptr, cursor, N);
    edge_fill<<<(2 * P + 255) / 256, 256, 0, stream>>>(ai, decay, cursor, ecol, ewgt, P);

    mfma_gemm<256, 128, true><<<dim3(1, rb, S_), 256, 0, stream>>>(
        feat1_bf, FIN, Wn0t, bn0, neigh_bf, NO, cnt, perm);
    gather_rows<0><<<N / 4, 256, 0, stream>>>(neigh_bf, rowptr, ecol, ewgt, feat1_bf, nullptr);

    // ---- pass 1 ----
    mfma_gemm<384, 256, true><<<dim3(2, rb, S_), 256, 0, stream>>>(
        feat1_bf, FIN, Wm1t, bm1, int1_bf, MO, cnt, perm);
    mfma_gemm<256, 128, true><<<dim3(1, rb, S_), 256, 0, stream>>>(
        int1_bf, MO, Wn1t, bn1, neigh_bf, NO, cnt, perm);
    gather_rows<1><<<N / 4, 256, 0, stream>>>(neigh_bf, rowptr, ecol, ewgt, nullptr, merged_f);

    // ---- head + charges ----
    final_kernel<<<(N * 64 + 255) / 256, 256, 0, stream>>>(
        int1_bf, merged_f, Wf, bf, species, out, N);
    charges_kernel<<<B, A, 0, stream>>>(out + 2 * (size_t)N, species, tc, out, N, A);
}

// Round 7
// 724.134 us; speedup vs baseline: 2.2688x; 1.5231x over previous
//
#include <hip/hip_runtime.h>
#include <hip/hip_bf16.h>
#include <math.h>

constexpr int S_  = 4;
constexpr int MO  = 256;
constexpr int NO  = 128;
constexpr int FIN = 384;
#define CUTOFF_F 5.2f

typedef short bf16x8 __attribute__((ext_vector_type(8)));   // 8 bf16 = 4 VGPRs
typedef float f32x16 __attribute__((ext_vector_type(16)));  // 32x32 MFMA acc

__device__ __forceinline__ float gelu_tanh(float x) {
    float u = 0.7978845608028654f * (x + 0.044715f * x * x * x);
    return 0.5f * x * (1.0f + tanhf(u));
}
__device__ __forceinline__ unsigned short f2bf(float x) {   // RNE
    unsigned u = __float_as_uint(x);
    u = (u + 0x7fffu + ((u >> 16) & 1u)) >> 16;
    return (unsigned short)u;
}
__device__ __forceinline__ float bf2f(unsigned short h) {
    return __uint_as_float(((unsigned)h) << 16);
}

// ---------------- decay ----------------
__global__ void decay_kernel(const float* __restrict__ dist, const float* __restrict__ fa_,
                             const float* __restrict__ pf_, float* __restrict__ decay, int P) {
    int i = blockIdx.x * blockDim.x + threadIdx.x;
    if (i >= P) return;
    float fa = fa_[0], pf = pf_[0];
    float d = dist[i];
    float x = fminf(fmaxf(d / CUTOFF_F, 0.0f), 1.0f - 1e-6f);
    float f = expf(1.0f - 1.0f / (1.0f - x * x));
    float w = (d < CUTOFF_F) ? f : 0.0f;
    decay[i] = pf * pf * expf(-(fa * fa) * d) * w;
}

// ---------------- species sort: block-local hist + scan + fill (no hot global atomics) ----------------
// bhist[b*4+s] = count of species s in block b's 256-element slice.
__global__ void species_hist(const int* __restrict__ sp, int* __restrict__ bhist, int N) {
    __shared__ int h[S_];
    int t = threadIdx.x, b = blockIdx.x;
    if (t < S_) h[t] = 0;
    __syncthreads();
    int i = b * 256 + t;
    if (i < N) {
        int s = sp[i];
        if (s >= 0 && s < S_) atomicAdd(&h[s], 1);   // LDS atomic, intra-block only
    }
    __syncthreads();
    if (t < S_) bhist[b * 4 + t] = h[t];
}
// single block; serial scan over nb*4 counts (<= ~512) — negligible.
// cnt layout preserved: [0..3]=counts, [4..7]=segment offsets.
__global__ void species_scan(const int* __restrict__ bhist, int* __restrict__ cnt,
                             int* __restrict__ pbase, int nb) {
    if (threadIdx.x != 0) return;
    int tot[S_];
    for (int s = 0; s < S_; ++s) {
        int sum = 0;
        for (int b = 0; b < nb; ++b) sum += bhist[b * 4 + s];
        tot[s] = sum;
    }
    int off = 0;
    for (int s = 0; s < S_; ++s) { cnt[s] = tot[s]; cnt[4 + s] = off; off += tot[s]; }
    for (int s = 0; s < S_; ++s) {
        int run = cnt[4 + s];
        for (int b = 0; b < nb; ++b) { pbase[b * 4 + s] = run; run += bhist[b * 4 + s]; }
    }
}
__global__ void species_fill(const int* __restrict__ sp, const int* __restrict__ pbase,
                             int* __restrict__ perm, int N) {
    __shared__ int cur[S_];
    int t = threadIdx.x, b = blockIdx.x;
    if (t < S_) cur[t] = pbase[b * 4 + t];
    __syncthreads();
    int i = b * 256 + t;
    if (i < N) {
        int s = sp[i];
        if (s >= 0 && s < S_) {
            int pos = atomicAdd(&cur[s], 1);         // LDS atomic
            perm[pos] = i;
        }
    }
}

// ---------------- edge CSR build (dst-sorted adjacency; atomics spread over N addrs) ----------------
__global__ void edge_count(const int* __restrict__ ai, int* __restrict__ degree, int P2) {
    int e = blockIdx.x * blockDim.x + threadIdx.x;
    if (e < P2) atomicAdd(&degree[ai[e]], 1);
}
__global__ void scan_rowptr(const int* __restrict__ degree, int* __restrict__ rowptr,
                            int* __restrict__ cursor, int N) {
    __shared__ int lds[1024];
    int t = threadIdx.x;
    int per = N / 1024;
    int base = t * per;
    int sum = 0;
    for (int i = 0; i < per; ++i) sum += degree[base + i];
    lds[t] = sum;
    __syncthreads();
    int v = sum;
    for (int ofs = 1; ofs < 1024; ofs <<= 1) {
        int add = (t >= ofs) ? lds[t - ofs] : 0;
        __syncthreads();
        v += add;
        lds[t] = v;
        __syncthreads();
    }
    int run = v - sum;   // exclusive prefix
    for (int i = 0; i < per; ++i) {
        int d = degree[base + i];
        rowptr[base + i] = run;
        cursor[base + i] = run;
        run += d;
    }
    if (t == 1023) rowptr[N] = run;
}
__global__ void edge_fill(const int* __restrict__ ai, const float* __restrict__ decay,
                          int* __restrict__ cursor, int* __restrict__ col,
                          float* __restrict__ wgt, int P) {
    int e = blockIdx.x * blockDim.x + threadIdx.x;
    if (e >= 2 * P) return;
    int p = (e < P) ? e : e - P;
    int dst = ai[e];
    int src = (e < P) ? ai[P + p] : ai[p];
    int pos = atomicAdd(&cursor[dst], 1);
    col[pos] = src;
    wgt[pos] = decay[p];
}

// ---------------- casts ----------------
__global__ void cast_aev(const float* __restrict__ in, unsigned short* __restrict__ outb, int total4) {
    int i = blockIdx.x * blockDim.x + threadIdx.x;
    if (i >= total4) return;
    float4 v = ((const float4*)in)[i];
    ushort4 o; o.x = f2bf(v.x); o.y = f2bf(v.y); o.z = f2bf(v.z); o.w = f2bf(v.w);
    ((ushort4*)outb)[i] = o;
}

// W [S][K][NC] fp32 -> Wt [S][NC][K] bf16
__global__ void transpose_cast(const float* __restrict__ W, unsigned short* __restrict__ Wt,
                               int K, int NC) {
    __shared__ float tile[32][33];
    int s = blockIdx.z;
    int nb = blockIdx.x * 32, kb = blockIdx.y * 32;
    int tx = threadIdx.x & 31, ty = threadIdx.x >> 5;
    const float* Wb = W + (size_t)s * K * NC;
    unsigned short* Wo = Wt + (size_t)s * NC * K;
#pragma unroll
    for (int i = 0; i < 4; ++i) {
        int k = kb + ty + i * 8;
        tile[ty + i * 8][tx] = (k < K) ? Wb[(size_t)k * NC + nb + tx] : 0.0f;
    }
    __syncthreads();
#pragma unroll
    for (int i = 0; i < 4; ++i) {
        int n = nb + ty + i * 8;
        int k = kb + tx;
        if (k < K) Wo[(size_t)n * K + k] = f2bf(tile[tx][ty + i * 8]);
    }
}

// ---------------- species-routed bf16 MFMA GEMM ----------------
template<int K, int NC, bool ACT>
__launch_bounds__(256, 2)
__global__ void mfma_gemm(const unsigned short* __restrict__ A, int lda,
                          const unsigned short* __restrict__ Wt,
                          const float* __restrict__ bias,
                          unsigned short* __restrict__ C, int ldc,
                          const int* __restrict__ cnt, const int* __restrict__ perm) {
    const int s = blockIdx.z;
    const int count = cnt[s];
    const int row0 = blockIdx.y * 128;
    if (row0 >= count) return;
    const int off = cnt[4 + s];
    const int c0 = blockIdx.x * 128;

    __shared__ unsigned short As[128 * 40];
    __shared__ unsigned short Bs[128 * 40];
    __shared__ int rix[128];

    const int t = threadIdx.x;
    const int lane = t & 63, wave = t >> 6;
    const int wm = wave >> 1, wn = wave & 1;
    const int l31 = lane & 31, lhi = lane >> 5;

    if (t < 128) {
        int ri = row0 + t;
        rix[t] = (ri < count) ? perm[off + ri] : -1;
    }
    __syncthreads();

    const int r2 = t >> 1, half = t & 1;
    const int gA = rix[r2];
    const unsigned short* wrow = Wt + ((size_t)s * NC + c0 + r2) * K;

    f32x16 acc00 = {}, acc01 = {}, acc10 = {}, acc11 = {};
    const float4 zf4 = make_float4(0.f, 0.f, 0.f, 0.f);

    for (int k0 = 0; k0 < K; k0 += 32) {
        const int kk = k0 + half * 16;
        const bool v = (kk < K);
        float4 a0 = zf4, a1 = zf4, b0 = zf4, b1 = zf4;
        if (v) {
            if (gA >= 0) {
                const float4* p = (const float4*)(A + (size_t)gA * lda + kk);
                a0 = p[0]; a1 = p[1];
            }
            const float4* q = (const float4*)(wrow + kk);
            b0 = q[0]; b1 = q[1];
        }
        __syncthreads();
        *(float4*)(&As[r2 * 40 + half * 16])     = a0;
        *(float4*)(&As[r2 * 40 + half * 16 + 8]) = a1;
        *(float4*)(&Bs[r2 * 40 + half * 16])     = b0;
        *(float4*)(&Bs[r2 * 40 + half * 16 + 8]) = b1;
        __syncthreads();
#pragma unroll
        for (int ks = 0; ks < 2; ++ks) {
            const int ch = (ks * 2 + lhi) * 8;
            bf16x8 fa0 = *(const bf16x8*)(&As[(wm * 64 +  0 + l31) * 40 + ch]);
            bf16x8 fa1 = *(const bf16x8*)(&As[(wm * 64 + 32 + l31) * 40 + ch]);
            bf16x8 fb0 = *(const bf16x8*)(&Bs[(wn * 64 +  0 + l31) * 40 + ch]);
            bf16x8 fb1 = *(const bf16x8*)(&Bs[(wn * 64 + 32 + l31) * 40 + ch]);
            acc00 = __builtin_amdgcn_mfma_f32_32x32x16_bf16(fa0, fb0, acc00, 0, 0, 0);
            acc01 = __builtin_amdgcn_mfma_f32_32x32x16_bf16(fa0, fb1, acc01, 0, 0, 0);
            acc10 = __builtin_amdgcn_mfma_f32_32x32x16_bf16(fa1, fb0, acc10, 0, 0, 0);
            acc11 = __builtin_amdgcn_mfma_f32_32x32x16_bf16(fa1, fb1, acc11, 0, 0, 0);
        }
    }

    const float* bp = bias + s * NC;
    auto store = [&](const f32x16& vv, int fm, int fn) {
        int col = c0 + wn * 64 + fn * 32 + l31;
        float bia = bp[col];
#pragma unroll
        for (int reg = 0; reg < 16; ++reg) {
            int frow = (reg & 3) + 8 * (reg >> 2) + 4 * lhi;
            int r = wm * 64 + fm * 32 + frow;
            int g = rix[r];
            if (g >= 0) {
                float x = vv[reg] + bia;
                if (ACT) x = gelu_tanh(x);
                C[(size_t)g * ldc + col] = f2bf(x);
            }
        }
    };
    store(acc00, 0, 0); store(acc01, 0, 1); store(acc10, 1, 0); store(acc11, 1, 1);
}

// ---------------- CSR gather-reduce ----------------
// One wave per dst row; lane owns 2 columns (ushort2 = 4 B).
// MODE 0: write bf16 into feat[:, MO:MO+NO];  MODE 1: write fp32 merged.
template<int MODE>
__global__ void gather_rows(const unsigned short* __restrict__ neigh,
                            const int* __restrict__ rowptr, const int* __restrict__ col,
                            const float* __restrict__ wgt,
                            unsigned short* __restrict__ featout,
                            float* __restrict__ mergedout) {
    int row = blockIdx.x * 4 + (threadIdx.x >> 6);
    int lane = threadIdx.x & 63;
    int b = rowptr[row], e = rowptr[row + 1];
    int j = lane * 2;
    float a0 = 0.f, a1 = 0.f;
    for (int i = b; i < e; ++i) {
        int src = col[i];
        float w = wgt[i];
        unsigned pk = *(const unsigned*)(neigh + (size_t)src * NO + j);
        a0 += bf2f((unsigned short)(pk & 0xffffu)) * w;
        a1 += bf2f((unsigned short)(pk >> 16)) * w;
    }
    if (MODE == 0) {
        unsigned short o0 = f2bf(a0), o1 = f2bf(a1);
        *(unsigned*)(featout + (size_t)row * FIN + MO + j) = ((unsigned)o1 << 16) | (unsigned)o0;
    } else {
        float2 o; o.x = a0; o.y = a1;
        *(float2*)(mergedout + (size_t)row * NO + j) = o;
    }
}

// ---------------- final head ----------------
__global__ void final_kernel(const unsigned short* __restrict__ int1, const float* __restrict__ merged,
                             const float* __restrict__ Wf, const float* __restrict__ bfb,
                             const int* __restrict__ species, float* __restrict__ out, int N) {
    int w = (int)((blockIdx.x * (size_t)blockDim.x + threadIdx.x) >> 6);
    int lane = threadIdx.x & 63;
    if (w >= N) return;
    int s = species[w];
    float acc = 0.0f;
    if (s >= 0) {
        const float* wp = Wf + (size_t)s * FIN;
        for (int k = lane; k < MO; k += 64) acc += bf2f(int1[(size_t)w * MO + k]) * wp[k];
        for (int k = lane; k < NO; k += 64) acc += merged[(size_t)w * NO + k] * wp[MO + k];
    }
    for (int o = 32; o > 0; o >>= 1) acc += __shfl_down(acc, o, 64);
    if (lane == 0) {
        float pre = (s >= 0) ? (acc + bfb[s]) : 0.0f;
        out[2 * (size_t)N + w] = pre;
        out[w] = (float)s;
    }
}

// ---------------- per-batch charge correction ----------------
__global__ void charges_kernel(const float* __restrict__ pre_buf, const int* __restrict__ species,
                               const float* __restrict__ tc, float* __restrict__ out, int N, int A) {
    int b = blockIdx.x;
    int a = threadIdx.x;
    int idx = b * A + a;
    float pre = pre_buf[idx];
    int sp = species[idx];
    bool mask = (sp != -1);
    float v = pre;
    int c = mask ? 1 : 0;
    for (int o = 32; o > 0; o >>= 1) {
        v += __shfl_down(v, o, 64);
        c += __shfl_down(c, o, 64);
    }
    __shared__ float ssum[2];
    __shared__ int scnt[2];
    int wid = threadIdx.x >> 6;
    if ((threadIdx.x & 63) == 0) { ssum[wid] = v; scnt[wid] = c; }
    __syncthreads();
    float total = ssum[0] + ssum[1];
    int nreal = scnt[0] + scnt[1];
    float ch = pre + (tc[b] - total) / (float)max(nreal, 1);
    out[(size_t)N + idx] = mask ? ch : 0.0f;
}

extern "C" void kernel_launch(void* const* d_in, const int* in_sizes, int n_in,
                              void* d_out, int out_size, void* d_ws, size_t ws_size,
                              hipStream_t stream) {
    const int*   species = (const int*)d_in[0];
    const float* aev     = (const float*)d_in[1];
    const int*   ai      = (const int*)d_in[2];
    const float* dist    = (const float*)d_in[3];
    const float* tc      = (const float*)d_in[4];
    const float* Wm0 = (const float*)d_in[5];  const float* bm0 = (const float*)d_in[6];
    const float* Wn0 = (const float*)d_in[7];  const float* bn0 = (const float*)d_in[8];
    const float* Wm1 = (const float*)d_in[9];  const float* bm1 = (const float*)d_in[10];
    const float* Wn1 = (const float*)d_in[11]; const float* bn1 = (const float*)d_in[12];
    const float* Wf  = (const float*)d_in[13]; const float* bf  = (const float*)d_in[14];
    const float* factor    = (const float*)d_in[15];
    const float* prefactor = (const float*)d_in[16];

    const int N   = in_sizes[0];
    const int AEV = in_sizes[1] / N;       // 1008
    const int P   = in_sizes[3];
    const int B   = in_sizes[4];
    const int A   = N / B;

    float* out = (float*)d_out;

    // ---- workspace layout ----
    char* base = (char*)d_ws;
    size_t o = 0;
    auto take = [&](size_t bytes) -> char* {
        o = (o + 255) & ~(size_t)255;
        char* p = base + o; o += bytes; return p;
    };
    unsigned short* feat1_bf = (unsigned short*)take((size_t)N * FIN * 2);
    unsigned short* int1_bf  = (unsigned short*)take((size_t)N * MO * 2);
    char* region             = take((size_t)N * AEV * 2);
    // region overlay:
    //   [0, 66MB)           aev_bf              (dead after gemm1)
    //   [0, 8MB)            neigh_bf            (gemm2/gemm4 output)
    //   [8MB, 24MB)         merged_f  (fp32, pass-1 only)
    //   [24MB, ~28.5MB)     CSR: rowptr, cursor, degree, col, wgt  (built after gemm1)
    unsigned short* aev_bf   = (unsigned short*)region;
    unsigned short* neigh_bf = (unsigned short*)region;
    size_t roff = ((size_t)N * NO * 2 + 255) & ~(size_t)255;
    float* merged_f = (float*)(region + roff);
    roff += (size_t)N * NO * 4;
    roff = (roff + 255) & ~(size_t)255;
    int* rowptr = (int*)(region + roff);  roff += (size_t)(N + 1) * 4; roff = (roff + 255) & ~(size_t)255;
    int* cursor = (int*)(region + roff);  roff += (size_t)N * 4;       roff = (roff + 255) & ~(size_t)255;
    int* degree = (int*)(region + roff);  roff += (size_t)N * 4;       roff = (roff + 255) & ~(size_t)255;
    int* ecol   = (int*)(region + roff);  roff += (size_t)2 * P * 4;   roff = (roff + 255) & ~(size_t)255;
    float* ewgt = (float*)(region + roff);
    float* decay = (float*)take((size_t)P * 4);
    unsigned short* Wm0t = (unsigned short*)take((size_t)S_ * MO * AEV * 2);
    unsigned short* Wn0t = (unsigned short*)take((size_t)S_ * NO * MO * 2);
    unsigned short* Wm1t = (unsigned short*)take((size_t)S_ * MO * FIN * 2);
    unsigned short* Wn1t = (unsigned short*)take((size_t)S_ * NO * MO * 2);
    int* perm  = (int*)take((size_t)N * 4);
    int* cnt   = (int*)take(64);
    const int nb = (N + 255) / 256;
    int* bhist = (int*)take((size_t)nb * 4 * 4);
    int* pbase = (int*)take((size_t)nb * 4 * 4);

    // ---- species sort (block-local, no hot global atomics) + decay + casts ----
    species_hist<<<nb, 256, 0, stream>>>(species, bhist, N);
    species_scan<<<1, 64, 0, stream>>>(bhist, cnt, pbase, nb);
    species_fill<<<nb, 256, 0, stream>>>(species, pbase, perm, N);
    decay_kernel<<<(P + 255) / 256, 256, 0, stream>>>(dist, factor, prefactor, decay, P);

    const int tot4 = N * (AEV / 4);
    cast_aev<<<(tot4 + 255) / 256, 256, 0, stream>>>(aev, aev_bf, tot4);
    transpose_cast<<<dim3(MO / 32, (AEV + 31) / 32, S_), 256, 0, stream>>>(Wm0, Wm0t, AEV, MO);
    transpose_cast<<<dim3(NO / 32, MO / 32, S_), 256, 0, stream>>>(Wn0, Wn0t, MO, NO);
    transpose_cast<<<dim3(MO / 32, FIN / 32, S_), 256, 0, stream>>>(Wm1, Wm1t, FIN, MO);
    transpose_cast<<<dim3(NO / 32, MO / 32, S_), 256, 0, stream>>>(Wn1, Wn1t, MO, NO);

    const int rb = (N + 127) / 128;

    // ---- pass 0: big GEMM first (aev_bf dies here), then CSR build in its memory ----
    mfma_gemm<1008, 256, true><<<dim3(2, rb, S_), 256, 0, stream>>>(
        aev_bf, AEV, Wm0t, bm0, feat1_bf, FIN, cnt, perm);

    hipMemsetAsync(degree, 0, (size_t)N * 4, stream);
    edge_count<<<(2 * P + 255) / 256, 256, 0, stream>>>(ai, degree, 2 * P);
    scan_rowptr<<<1, 1024, 0, stream>>>(degree, rowptr, cursor, N);
    edge_fill<<<(2 * P + 255) / 256, 256, 0, stream>>>(ai, decay, cursor, ecol, ewgt, P);

    mfma_gemm<256, 128, true><<<dim3(1, rb, S_), 256, 0, stream>>>(
        feat1_bf, FIN, Wn0t, bn0, neigh_bf, NO, cnt, perm);
    gather_rows<0><<<N / 4, 256, 0, stream>>>(neigh_bf, rowptr, ecol, ewgt, feat1_bf, nullptr);

    // ---- pass 1 ----
    mfma_gemm<384, 256, true><<<dim3(2, rb, S_), 256, 0, stream>>>(
        feat1_bf, FIN, Wm1t, bm1, int1_bf, MO, cnt, perm);
    mfma_gemm<256, 128, true><<<dim3(1, rb, S_), 256, 0, stream>>>(
        int1_bf, MO, Wn1t, bn1, neigh_bf, NO, cnt, perm);
    gather_rows<1><<<N / 4, 256, 0, stream>>>(neigh_bf, rowptr, ecol, ewgt, nullptr, merged_f);

    // ---- head + charges ----
    final_kernel<<<(N * 64 + 255) / 256, 256, 0, stream>>>(
        int1_bf, merged_f, Wf, bf, species, out, N);
    charges_kernel<<<B, A, 0, stream>>>(out + 2 * (size_t)N, species, tc, out, N, A);
}

// Round 8
// 691.248 us; speedup vs baseline: 2.3768x; 1.0476x over previous
//
#include <hip/hip_runtime.h>
#include <hip/hip_bf16.h>
#include <math.h>

constexpr int S_  = 4;
constexpr int MO  = 256;
constexpr int NO  = 128;
constexpr int FIN = 384;
#define CUTOFF_F 5.2f

typedef short bf16x8 __attribute__((ext_vector_type(8)));   // 8 bf16 = 4 VGPRs
typedef float f32x16 __attribute__((ext_vector_type(16)));  // 32x32 MFMA acc

__device__ __forceinline__ float gelu_tanh(float x) {
    float u = 0.7978845608028654f * (x + 0.044715f * x * x * x);
    return 0.5f * x * (1.0f + tanhf(u));
}
__device__ __forceinline__ unsigned short f2bf(float x) {   // RNE
    unsigned u = __float_as_uint(x);
    u = (u + 0x7fffu + ((u >> 16) & 1u)) >> 16;
    return (unsigned short)u;
}
__device__ __forceinline__ float bf2f(unsigned short h) {
    return __uint_as_float(((unsigned)h) << 16);
}

// ---------------- decay ----------------
__global__ void decay_kernel(const float* __restrict__ dist, const float* __restrict__ fa_,
                             const float* __restrict__ pf_, float* __restrict__ decay, int P) {
    int i = blockIdx.x * blockDim.x + threadIdx.x;
    if (i >= P) return;
    float fa = fa_[0], pf = pf_[0];
    float d = dist[i];
    float x = fminf(fmaxf(d / CUTOFF_F, 0.0f), 1.0f - 1e-6f);
    float f = expf(1.0f - 1.0f / (1.0f - x * x));
    float w = (d < CUTOFF_F) ? f : 0.0f;
    decay[i] = pf * pf * expf(-(fa * fa) * d) * w;
}

// ---------------- species sort: block-local hist + scan + fill ----------------
__global__ void species_hist(const int* __restrict__ sp, int* __restrict__ bhist, int N) {
    __shared__ int h[S_];
    int t = threadIdx.x, b = blockIdx.x;
    if (t < S_) h[t] = 0;
    __syncthreads();
    int i = b * 256 + t;
    if (i < N) {
        int s = sp[i];
        if (s >= 0 && s < S_) atomicAdd(&h[s], 1);   // LDS atomic
    }
    __syncthreads();
    if (t < S_) bhist[b * 4 + t] = h[t];
}
__global__ void species_scan(const int* __restrict__ bhist, int* __restrict__ cnt,
                             int* __restrict__ pbase, int nb) {
    if (threadIdx.x != 0) return;
    int tot[S_];
    for (int s = 0; s < S_; ++s) {
        int sum = 0;
        for (int b = 0; b < nb; ++b) sum += bhist[b * 4 + s];
        tot[s] = sum;
    }
    int off = 0;
    for (int s = 0; s < S_; ++s) { cnt[s] = tot[s]; cnt[4 + s] = off; off += tot[s]; }
    for (int s = 0; s < S_; ++s) {
        int run = cnt[4 + s];
        for (int b = 0; b < nb; ++b) { pbase[b * 4 + s] = run; run += bhist[b * 4 + s]; }
    }
}
__global__ void species_fill(const int* __restrict__ sp, const int* __restrict__ pbase,
                             int* __restrict__ perm, int N) {
    __shared__ int cur[S_];
    int t = threadIdx.x, b = blockIdx.x;
    if (t < S_) cur[t] = pbase[b * 4 + t];
    __syncthreads();
    int i = b * 256 + t;
    if (i < N) {
        int s = sp[i];
        if (s >= 0 && s < S_) {
            int pos = atomicAdd(&cur[s], 1);         // LDS atomic
            perm[pos] = i;
        }
    }
}

// ---------------- edge CSR build ----------------
__global__ void edge_count(const int* __restrict__ ai, int* __restrict__ degree, int P2) {
    int e = blockIdx.x * blockDim.x + threadIdx.x;
    if (e < P2) atomicAdd(&degree[ai[e]], 1);
}
__global__ void scan_rowptr(const int* __restrict__ degree, int* __restrict__ rowptr,
                            int* __restrict__ cursor, int N) {
    __shared__ int lds[1024];
    int t = threadIdx.x;
    int per = N / 1024;
    int base = t * per;
    int sum = 0;
    for (int i = 0; i < per; ++i) sum += degree[base + i];
    lds[t] = sum;
    __syncthreads();
    int v = sum;
    for (int ofs = 1; ofs < 1024; ofs <<= 1) {
        int add = (t >= ofs) ? lds[t - ofs] : 0;
        __syncthreads();
        v += add;
        lds[t] = v;
        __syncthreads();
    }
    int run = v - sum;   // exclusive prefix
    for (int i = 0; i < per; ++i) {
        int d = degree[base + i];
        rowptr[base + i] = run;
        cursor[base + i] = run;
        run += d;
    }
    if (t == 1023) rowptr[N] = run;
}
__global__ void edge_fill(const int* __restrict__ ai, const float* __restrict__ decay,
                          int* __restrict__ cursor, int* __restrict__ col,
                          float* __restrict__ wgt, int P) {
    int e = blockIdx.x * blockDim.x + threadIdx.x;
    if (e >= 2 * P) return;
    int p = (e < P) ? e : e - P;
    int dst = ai[e];
    int src = (e < P) ? ai[P + p] : ai[p];
    int pos = atomicAdd(&cursor[dst], 1);
    col[pos] = src;
    wgt[pos] = decay[p];
}

// ---------------- weight transpose+cast:  W [S][K][NC] fp32 -> Wt [S][NC][K] bf16 ----------------
__global__ void transpose_cast(const float* __restrict__ W, unsigned short* __restrict__ Wt,
                               int K, int NC) {
    __shared__ float tile[32][33];
    int s = blockIdx.z;
    int nb = blockIdx.x * 32, kb = blockIdx.y * 32;
    int tx = threadIdx.x & 31, ty = threadIdx.x >> 5;
    const float* Wb = W + (size_t)s * K * NC;
    unsigned short* Wo = Wt + (size_t)s * NC * K;
#pragma unroll
    for (int i = 0; i < 4; ++i) {
        int k = kb + ty + i * 8;
        tile[ty + i * 8][tx] = (k < K) ? Wb[(size_t)k * NC + nb + tx] : 0.0f;
    }
    __syncthreads();
#pragma unroll
    for (int i = 0; i < 4; ++i) {
        int n = nb + ty + i * 8;
        int k = kb + tx;
        if (k < K) Wo[(size_t)n * K + k] = f2bf(tile[tx][ty + i * 8]);
    }
}

// ---------------- species-routed bf16 MFMA GEMM, double-buffered 2-phase pipeline ----------------
// One barrier per K-step; prefetch of tile t+1 issued before MFMA of tile t so
// HBM latency hides under compute. AF32: A source is fp32 (cast fused into staging).
template<int K, int NC, bool ACT, bool AF32>
__launch_bounds__(256, 2)
__global__ void mfma_gemm(const void* __restrict__ Aptr, int lda,
                          const unsigned short* __restrict__ Wt,
                          const float* __restrict__ bias,
                          unsigned short* __restrict__ C, int ldc,
                          const int* __restrict__ cnt, const int* __restrict__ perm) {
    const int s = blockIdx.z;
    const int count = cnt[s];
    const int row0 = blockIdx.y * 128;
    if (row0 >= count) return;
    const int off = cnt[4 + s];
    const int c0 = blockIdx.x * 128;

    __shared__ unsigned short As[2][128 * 40];   // row stride 40 bf16 = 80 B (16B-aligned)
    __shared__ unsigned short Bs[2][128 * 40];
    __shared__ int rix[128];

    const int t = threadIdx.x;
    const int lane = t & 63, wave = t >> 6;
    const int wm = wave >> 1, wn = wave & 1;
    const int l31 = lane & 31, lhi = lane >> 5;

    if (t < 128) {
        int ri = row0 + t;
        rix[t] = (ri < count) ? perm[off + ri] : -1;
    }
    __syncthreads();

    const int r2 = t >> 1, half = t & 1;      // 2 threads per LDS row, 16 k-elems each
    const int gA = rix[r2];
    const unsigned short* wrow = Wt + ((size_t)s * NC + c0 + r2) * K;

    f32x16 acc00 = {}, acc01 = {}, acc10 = {}, acc11 = {};

    // prefetch registers (raw 16B words for bf16; 4 float4 for fp32 A)
    uint4 pa0 = {0,0,0,0}, pa1 = {0,0,0,0}, pb0 = {0,0,0,0}, pb1 = {0,0,0,0};
    float4 fa0{}, fa1{}, fa2{}, fa3{};

    auto prefetch = [&](int it) {
        const int kk = it * 32 + half * 16;
        const bool v = (kk < K);
        uint4 z = {0,0,0,0};
        pb0 = z; pb1 = z;
        if (v) {
            const uint4* q = (const uint4*)(wrow + kk);
            pb0 = q[0]; pb1 = q[1];
        }
        if (AF32) {
            float4 zf = make_float4(0.f,0.f,0.f,0.f);
            fa0 = zf; fa1 = zf; fa2 = zf; fa3 = zf;
            if (v && gA >= 0) {
                const float4* p = (const float4*)((const float*)Aptr + (size_t)gA * lda + kk);
                fa0 = p[0]; fa1 = p[1]; fa2 = p[2]; fa3 = p[3];
            }
        } else {
            pa0 = z; pa1 = z;
            if (v && gA >= 0) {
                const uint4* p = (const uint4*)((const unsigned short*)Aptr + (size_t)gA * lda + kk);
                pa0 = p[0]; pa1 = p[1];
            }
        }
    };
    auto stage = [&](int buf) {
        uint4 aw0, aw1;
        if (AF32) {
            union { unsigned short us[8]; uint4 v; } k0, k1;
            const float* f0 = (const float*)&fa0;
            const float* f1 = (const float*)&fa1;
            const float* f2 = (const float*)&fa2;
            const float* f3 = (const float*)&fa3;
#pragma unroll
            for (int i = 0; i < 4; ++i) { k0.us[i] = f2bf(f0[i]); k0.us[4 + i] = f2bf(f1[i]); }
#pragma unroll
            for (int i = 0; i < 4; ++i) { k1.us[i] = f2bf(f2[i]); k1.us[4 + i] = f2bf(f3[i]); }
            aw0 = k0.v; aw1 = k1.v;
        } else {
            aw0 = pa0; aw1 = pa1;
        }
        *(uint4*)(&As[buf][r2 * 40 + half * 16])     = aw0;
        *(uint4*)(&As[buf][r2 * 40 + half * 16 + 8]) = aw1;
        *(uint4*)(&Bs[buf][r2 * 40 + half * 16])     = pb0;
        *(uint4*)(&Bs[buf][r2 * 40 + half * 16 + 8]) = pb1;
    };

    const int NIT = (K + 31) / 32;
    prefetch(0);
    stage(0);
    int cur = 0;

    for (int it = 0; it < NIT; ++it) {
        __syncthreads();                       // stage(cur) visible; prev MFMA on cur^1 done
        const bool more = (it + 1 < NIT);
        if (more) prefetch(it + 1);            // issue loads; vmcnt waited only at stage() below
#pragma unroll
        for (int ks = 0; ks < 2; ++ks) {
            const int ch = (ks * 2 + lhi) * 8;
            bf16x8 a0 = *(const bf16x8*)(&As[cur][(wm * 64 +  0 + l31) * 40 + ch]);
            bf16x8 a1 = *(const bf16x8*)(&As[cur][(wm * 64 + 32 + l31) * 40 + ch]);
            bf16x8 b0 = *(const bf16x8*)(&Bs[cur][(wn * 64 +  0 + l31) * 40 + ch]);
            bf16x8 b1 = *(const bf16x8*)(&Bs[cur][(wn * 64 + 32 + l31) * 40 + ch]);
            acc00 = __builtin_amdgcn_mfma_f32_32x32x16_bf16(a0, b0, acc00, 0, 0, 0);
            acc01 = __builtin_amdgcn_mfma_f32_32x32x16_bf16(a0, b1, acc01, 0, 0, 0);
            acc10 = __builtin_amdgcn_mfma_f32_32x32x16_bf16(a1, b0, acc10, 0, 0, 0);
            acc11 = __builtin_amdgcn_mfma_f32_32x32x16_bf16(a1, b1, acc11, 0, 0, 0);
        }
        if (more) stage(cur ^ 1);              // safe: cur^1's readers finished before barrier
        cur ^= 1;
    }

    const float* bp = bias + s * NC;
    auto store = [&](const f32x16& vv, int fm, int fn) {
        int col = c0 + wn * 64 + fn * 32 + l31;
        float bia = bp[col];
#pragma unroll
        for (int reg = 0; reg < 16; ++reg) {
            int frow = (reg & 3) + 8 * (reg >> 2) + 4 * lhi;   // verified C/D layout
            int r = wm * 64 + fm * 32 + frow;
            int g = rix[r];
            if (g >= 0) {
                float x = vv[reg] + bia;
                if (ACT) x = gelu_tanh(x);
                C[(size_t)g * ldc + col] = f2bf(x);
            }
        }
    };
    store(acc00, 0, 0); store(acc01, 0, 1); store(acc10, 1, 0); store(acc11, 1, 1);
}

// ---------------- CSR gather-reduce ----------------
template<int MODE>
__global__ void gather_rows(const unsigned short* __restrict__ neigh,
                            const int* __restrict__ rowptr, const int* __restrict__ col,
                            const float* __restrict__ wgt,
                            unsigned short* __restrict__ featout,
                            float* __restrict__ mergedout) {
    int row = blockIdx.x * 4 + (threadIdx.x >> 6);
    int lane = threadIdx.x & 63;
    int b = rowptr[row], e = rowptr[row + 1];
    int j = lane * 2;
    float a0 = 0.f, a1 = 0.f;
    for (int i = b; i < e; ++i) {
        int src = col[i];
        float w = wgt[i];
        unsigned pk = *(const unsigned*)(neigh + (size_t)src * NO + j);
        a0 += bf2f((unsigned short)(pk & 0xffffu)) * w;
        a1 += bf2f((unsigned short)(pk >> 16)) * w;
    }
    if (MODE == 0) {
        unsigned short o0 = f2bf(a0), o1 = f2bf(a1);
        *(unsigned*)(featout + (size_t)row * FIN + MO + j) = ((unsigned)o1 << 16) | (unsigned)o0;
    } else {
        float2 o; o.x = a0; o.y = a1;
        *(float2*)(mergedout + (size_t)row * NO + j) = o;
    }
}

// ---------------- final head ----------------
__global__ void final_kernel(const unsigned short* __restrict__ int1, const float* __restrict__ merged,
                             const float* __restrict__ Wf, const float* __restrict__ bfb,
                             const int* __restrict__ species, float* __restrict__ out, int N) {
    int w = (int)((blockIdx.x * (size_t)blockDim.x + threadIdx.x) >> 6);
    int lane = threadIdx.x & 63;
    if (w >= N) return;
    int s = species[w];
    float acc = 0.0f;
    if (s >= 0) {
        const float* wp = Wf + (size_t)s * FIN;
        for (int k = lane; k < MO; k += 64) acc += bf2f(int1[(size_t)w * MO + k]) * wp[k];
        for (int k = lane; k < NO; k += 64) acc += merged[(size_t)w * NO + k] * wp[MO + k];
    }
    for (int o = 32; o > 0; o >>= 1) acc += __shfl_down(acc, o, 64);
    if (lane == 0) {
        float pre = (s >= 0) ? (acc + bfb[s]) : 0.0f;
        out[2 * (size_t)N + w] = pre;
        out[w] = (float)s;
    }
}

// ---------------- per-batch charge correction ----------------
__global__ void charges_kernel(const float* __restrict__ pre_buf, const int* __restrict__ species,
                               const float* __restrict__ tc, float* __restrict__ out, int N, int A) {
    int b = blockIdx.x;
    int a = threadIdx.x;
    int idx = b * A + a;
    float pre = pre_buf[idx];
    int sp = species[idx];
    bool mask = (sp != -1);
    float v = pre;
    int c = mask ? 1 : 0;
    for (int o = 32; o > 0; o >>= 1) {
        v += __shfl_down(v, o, 64);
        c += __shfl_down(c, o, 64);
    }
    __shared__ float ssum[2];
    __shared__ int scnt[2];
    int wid = threadIdx.x >> 6;
    if ((threadIdx.x & 63) == 0) { ssum[wid] = v; scnt[wid] = c; }
    __syncthreads();
    float total = ssum[0] + ssum[1];
    int nreal = scnt[0] + scnt[1];
    float ch = pre + (tc[b] - total) / (float)max(nreal, 1);
    out[(size_t)N + idx] = mask ? ch : 0.0f;
}

extern "C" void kernel_launch(void* const* d_in, const int* in_sizes, int n_in,
                              void* d_out, int out_size, void* d_ws, size_t ws_size,
                              hipStream_t stream) {
    const int*   species = (const int*)d_in[0];
    const float* aev     = (const float*)d_in[1];
    const int*   ai      = (const int*)d_in[2];
    const float* dist    = (const float*)d_in[3];
    const float* tc      = (const float*)d_in[4];
    const float* Wm0 = (const float*)d_in[5];  const float* bm0 = (const float*)d_in[6];
    const float* Wn0 = (const float*)d_in[7];  const float* bn0 = (const float*)d_in[8];
    const float* Wm1 = (const float*)d_in[9];  const float* bm1 = (const float*)d_in[10];
    const float* Wn1 = (const float*)d_in[11]; const float* bn1 = (const float*)d_in[12];
    const float* Wf  = (const float*)d_in[13]; const float* bf  = (const float*)d_in[14];
    const float* factor    = (const float*)d_in[15];
    const float* prefactor = (const float*)d_in[16];

    const int N   = in_sizes[0];
    const int AEV = in_sizes[1] / N;       // 1008
    const int P   = in_sizes[3];
    const int B   = in_sizes[4];
    const int A   = N / B;

    float* out = (float*)d_out;

    // ---- workspace layout ----
    char* base = (char*)d_ws;
    size_t o = 0;
    auto take = [&](size_t bytes) -> char* {
        o = (o + 255) & ~(size_t)255;
        char* p = base + o; o += bytes; return p;
    };
    unsigned short* feat1_bf = (unsigned short*)take((size_t)N * FIN * 2);
    unsigned short* int1_bf  = (unsigned short*)take((size_t)N * MO * 2);
    char* region             = take((size_t)N * AEV * 2);
    // region overlay: neigh_bf | merged_f | CSR arrays (no aev_bf anymore — cast fused)
    unsigned short* neigh_bf = (unsigned short*)region;
    size_t roff = ((size_t)N * NO * 2 + 255) & ~(size_t)255;
    float* merged_f = (float*)(region + roff);
    roff += (size_t)N * NO * 4;
    roff = (roff + 255) & ~(size_t)255;
    int* rowptr = (int*)(region + roff);  roff += (size_t)(N + 1) * 4; roff = (roff + 255) & ~(size_t)255;
    int* cursor = (int*)(region + roff);  roff += (size_t)N * 4;       roff = (roff + 255) & ~(size_t)255;
    int* degree = (int*)(region + roff);  roff += (size_t)N * 4;       roff = (roff + 255) & ~(size_t)255;
    int* ecol   = (int*)(region + roff);  roff += (size_t)2 * P * 4;   roff = (roff + 255) & ~(size_t)255;
    float* ewgt = (float*)(region + roff);
    float* decay = (float*)take((size_t)P * 4);
    unsigned short* Wm0t = (unsigned short*)take((size_t)S_ * MO * AEV * 2);
    unsigned short* Wn0t = (unsigned short*)take((size_t)S_ * NO * MO * 2);
    unsigned short* Wm1t = (unsigned short*)take((size_t)S_ * MO * FIN * 2);
    unsigned short* Wn1t = (unsigned short*)take((size_t)S_ * NO * MO * 2);
    int* perm  = (int*)take((size_t)N * 4);
    int* cnt   = (int*)take(64);
    const int nb = (N + 255) / 256;
    int* bhist = (int*)take((size_t)nb * 4 * 4);
    int* pbase = (int*)take((size_t)nb * 4 * 4);

    // ---- species sort + decay + weight transposes; CSR build early (independent) ----
    species_hist<<<nb, 256, 0, stream>>>(species, bhist, N);
    species_scan<<<1, 64, 0, stream>>>(bhist, cnt, pbase, nb);
    species_fill<<<nb, 256, 0, stream>>>(species, pbase, perm, N);
    decay_kernel<<<(P + 255) / 256, 256, 0, stream>>>(dist, factor, prefactor, decay, P);

    hipMemsetAsync(degree, 0, (size_t)N * 4, stream);
    edge_count<<<(2 * P + 255) / 256, 256, 0, stream>>>(ai, degree, 2 * P);
    scan_rowptr<<<1, 1024, 0, stream>>>(degree, rowptr, cursor, N);
    edge_fill<<<(2 * P + 255) / 256, 256, 0, stream>>>(ai, decay, cursor, ecol, ewgt, P);

    transpose_cast<<<dim3(MO / 32, (AEV + 31) / 32, S_), 256, 0, stream>>>(Wm0, Wm0t, AEV, MO);
    transpose_cast<<<dim3(NO / 32, MO / 32, S_), 256, 0, stream>>>(Wn0, Wn0t, MO, NO);
    transpose_cast<<<dim3(MO / 32, FIN / 32, S_), 256, 0, stream>>>(Wm1, Wm1t, FIN, MO);
    transpose_cast<<<dim3(NO / 32, MO / 32, S_), 256, 0, stream>>>(Wn1, Wn1t, MO, NO);

    const int rb = (N + 127) / 128;

    // ---- pass 0 (GEMM1 reads fp32 aev directly; cast fused into staging) ----
    mfma_gemm<1008, 256, true, true><<<dim3(2, rb, S_), 256, 0, stream>>>(
        aev, AEV, Wm0t, bm0, feat1_bf, FIN, cnt, perm);
    mfma_gemm<256, 128, true, false><<<dim3(1, rb, S_), 256, 0, stream>>>(
        feat1_bf, FIN, Wn0t, bn0, neigh_bf, NO, cnt, perm);
    gather_rows<0><<<N / 4, 256, 0, stream>>>(neigh_bf, rowptr, ecol, ewgt, feat1_bf, nullptr);

    // ---- pass 1 ----
    mfma_gemm<384, 256, true, false><<<dim3(2, rb, S_), 256, 0, stream>>>(
        feat1_bf, FIN, Wm1t, bm1, int1_bf, MO, cnt, perm);
    mfma_gemm<256, 128, true, false><<<dim3(1, rb, S_), 256, 0, stream>>>(
        int1_bf, MO, Wn1t, bn1, neigh_bf, NO, cnt, perm);
    gather_rows<1><<<N / 4, 256, 0, stream>>>(neigh_bf, rowptr, ecol, ewgt, nullptr, merged_f);

    // ---- head + charges ----
    final_kernel<<<(N * 64 + 255) / 256, 256, 0, stream>>>(
        int1_bf, merged_f, Wf, bf, species, out, N);
    charges_kernel<<<B, A, 0, stream>>>(out + 2 * (size_t)N, species, tc, out, N, A);
}